// Round 1
// baseline (499.733 us; speedup 1.0000x reference)
//
#include <hip/hip_runtime.h>
#include <hip/hip_bf16.h>

#pragma clang fp contract(off)

#define NB 8
#define NG 64
#define NA 33600
#define KTOP 9
#define NCAND 27
#define NPRO 31
#define NALP 24
#define NADS 37

// _pairwise_iou semantics: unclipped areas, union = max(a1+a2-ov, 1e-6)
__device__ __forceinline__ float pair_iou(float x1, float y1, float x2, float y2,
                                          float ax1, float ay1, float ax2, float ay2) {
    float a1 = (x2 - x1) * (y2 - y1);
    float a2 = (ax2 - ax1) * (ay2 - ay1);
    float w = fminf(x2, ax2) - fmaxf(x1, ax1); w = fmaxf(w, 0.0f);
    float h = fminf(y2, ay2) - fmaxf(y1, ay1); h = fmaxf(h, 0.0f);
    float ov = w * h;
    float un = a1 + a2 - ov; un = fmaxf(un, 1e-6f);
    return ov / un;
}

// Kernel 1: one block per (b,g). Top-9 per level by (distance, index) lex order,
// ATSS threshold, set bit g in gbits[b*NA + a] for each positive anchor.
__global__ __launch_bounds__(256) void k_cand(
    const float* __restrict__ anc,     // NA x 4
    const float* __restrict__ gt,      // NB x NG x 4
    const float* __restrict__ mgt,     // NB x NG
    unsigned long long* __restrict__ gbits) // NB x NA
{
    int bg = blockIdx.x;
    int b = bg >> 6;
    int g = bg & 63;
    if (mgt[bg] <= 0.0f) return;  // invalid gt contributes nothing downstream

    const float x1 = gt[bg * 4 + 0], y1 = gt[bg * 4 + 1];
    const float x2 = gt[bg * 4 + 2], y2 = gt[bg * 4 + 3];
    const float gx = (x1 + x2) * 0.5f, gy = (y1 + y2) * 0.5f;

    __shared__ float sd[256][KTOP];
    __shared__ int   si[256][KTOP];
    __shared__ int   cand[NCAND];

    const int tid = threadIdx.x;
    const int starts[3] = {0, 25600, 32000};
    const int lens[3]   = {25600, 6400, 1600};

    for (int lev = 0; lev < 3; ++lev) {
        float d9[KTOP]; int i9[KTOP];
        #pragma unroll
        for (int j = 0; j < KTOP; ++j) { d9[j] = INFINITY; i9[j] = 0x7fffffff; }

        const int s = starts[lev], L = lens[lev];
        for (int li = tid; li < L; li += 256) {
            int a = s + li;
            float ax = (anc[a * 4 + 0] + anc[a * 4 + 2]) * 0.5f;
            float ay = (anc[a * 4 + 1] + anc[a * 4 + 3]) * 0.5f;
            float dx = gx - ax, dy = gy - ay;
            float d = sqrtf(dx * dx + dy * dy);
            if (d < d9[KTOP - 1] || (d == d9[KTOP - 1] && li < i9[KTOP - 1])) {
                int j = KTOP - 1;
                while (j > 0 && (d < d9[j - 1] || (d == d9[j - 1] && li < i9[j - 1]))) {
                    d9[j] = d9[j - 1]; i9[j] = i9[j - 1]; --j;
                }
                d9[j] = d; i9[j] = li;
            }
        }

        // tree merge of per-thread sorted top-9 lists
        for (int off = 128; off >= 1; off >>= 1) {
            #pragma unroll
            for (int j = 0; j < KTOP; ++j) { sd[tid][j] = d9[j]; si[tid][j] = i9[j]; }
            __syncthreads();
            if (tid < off) {
                float md[KTOP]; int mi[KTOP];
                int p = 0, q = 0;
                #pragma unroll
                for (int j = 0; j < KTOP; ++j) {
                    float da = d9[p];            int ia = i9[p];
                    float db = sd[tid + off][q]; int ib = si[tid + off][q];
                    bool takeA = (da < db) || (da == db && ia <= ib);
                    if (takeA) { md[j] = da; mi[j] = ia; ++p; }
                    else       { md[j] = db; mi[j] = ib; ++q; }
                }
                #pragma unroll
                for (int j = 0; j < KTOP; ++j) { d9[j] = md[j]; i9[j] = mi[j]; }
            }
            __syncthreads();
        }
        if (tid == 0) {
            #pragma unroll
            for (int j = 0; j < KTOP; ++j) cand[lev * KTOP + j] = s + i9[j];
        }
        __syncthreads();
    }

    if (tid == 0) {
        float co[NCAND];
        float sum = 0.0f;
        for (int j = 0; j < NCAND; ++j) {
            int a = cand[j];
            co[j] = pair_iou(x1, y1, x2, y2,
                             anc[a * 4 + 0], anc[a * 4 + 1], anc[a * 4 + 2], anc[a * 4 + 3]);
            sum += co[j];
        }
        float m = sum / 27.0f;
        float v = 0.0f;
        for (int j = 0; j < NCAND; ++j) { float dd = co[j] - m; v += dd * dd; }
        float thr = m + sqrtf(v / 26.0f);  // ddof=1
        for (int j = 0; j < NCAND; ++j) {
            if (co[j] > thr) {
                int a = cand[j];
                float ax = (anc[a * 4 + 0] + anc[a * 4 + 2]) * 0.5f;
                float ay = (anc[a * 4 + 1] + anc[a * 4 + 3]) * 0.5f;
                float mn = fminf(fminf(ax - x1, ay - y1), fminf(x2 - ax, y2 - ay));
                if (mn > 1e-9f) {  // is_in_gts, strict
                    atomicOr(&gbits[(unsigned long long)b * NA + a], 1ull << g);
                }
            }
        }
    }
}

// Kernel 2: one thread per (b, anchor). Resolve multi-assignment via argmax
// overlap, gather targets, scatter one-hot*iou scores (output pre-zeroed).
__global__ __launch_bounds__(256) void k_assign(
    const float* __restrict__ anc,
    const float* __restrict__ gt_pro,   // NB x NG
    const float* __restrict__ gt_alp,   // NB x NG
    const float* __restrict__ gt_ads,   // NB x NG x 6
    const float* __restrict__ gt,       // NB x NG x 4
    const float* __restrict__ gt_cn,    // NB x NG x 8
    const float* __restrict__ pd,       // NB x NA x 4
    const unsigned long long* __restrict__ gbits,
    float* __restrict__ out)
{
    const int t = blockIdx.x * 256 + threadIdx.x;
    if (t >= NB * NA) return;
    const int b = t / NA;
    const int a = t - b * NA;

    unsigned long long m = gbits[t];
    int fg = __popcll(m);
    if (fg > 1) {
        // replace with one-hot at argmax_g overlaps[b, :, a] (ties -> lowest g)
        float ax1 = anc[a * 4 + 0], ay1 = anc[a * 4 + 1];
        float ax2 = anc[a * 4 + 2], ay2 = anc[a * 4 + 3];
        float aarea = (ax2 - ax1) * (ay2 - ay1);
        float best = -INFINITY; int bgi = 0;
        for (int g = 0; g < NG; ++g) {
            const float* G = gt + ((size_t)b * NG + g) * 4;
            float gx1 = G[0], gy1 = G[1], gx2 = G[2], gy2 = G[3];
            float a1 = (gx2 - gx1) * (gy2 - gy1);
            float w = fminf(gx2, ax2) - fmaxf(gx1, ax1); w = fmaxf(w, 0.0f);
            float h = fminf(gy2, ay2) - fmaxf(gy1, ay1); h = fmaxf(h, 0.0f);
            float ov = w * h;
            float un = a1 + aarea - ov; un = fmaxf(un, 1e-6f);
            float iou = ov / un;
            if (iou > best) { best = iou; bgi = g; }
        }
        m = 1ull << bgi;
    }
    const bool fgb = (m != 0ull);
    const int tg = fgb ? (__ffsll((unsigned long long)m) - 1) : 0;

    const size_t row = (size_t)b * NG + tg;
    const float bx1 = gt[row * 4 + 0], by1 = gt[row * 4 + 1];
    const float bx2 = gt[row * 4 + 2], by2 = gt[row * 4 + 3];
    const float pro = gt_pro[row];
    const float alp = gt_alp[row];

    // _batched_iou(gt, pd): clipped areas, union + 1e-9
    float iou_pd = 0.0f;
    if (fgb) {
        const float* P = pd + ((size_t)b * NA + a) * 4;
        float px1 = P[0], py1 = P[1], px2 = P[2], py2 = P[3];
        float w = fminf(bx2, px2) - fmaxf(bx1, px1); w = fmaxf(w, 0.0f);
        float h = fminf(by2, py2) - fmaxf(by1, py1); h = fmaxf(h, 0.0f);
        float ov = w * h;
        float a1 = fmaxf(bx2 - bx1, 0.0f) * fmaxf(by2 - by1, 0.0f);
        float a2 = fmaxf(px2 - px1, 0.0f) * fmaxf(py2 - py1, 0.0f);
        iou_pd = ov / (a1 + a2 - ov + 1e-9f);
    }

    const size_t S0 = (size_t)NB * NA;  // 268800

    // target_pro / target_alp / target_ads[0..5]  (int values written as float)
    out[t] = fgb ? pro : (float)NPRO;
    out[S0 + t] = fgb ? alp : (float)NALP;
    float adsv[6];
    #pragma unroll
    for (int i = 0; i < 6; ++i) {
        adsv[i] = gt_ads[row * 6 + i];
        out[S0 * (2 + i) + t] = fgb ? adsv[i] : (float)NADS;
    }
    // target_bboxes (gathered regardless of fgb)
    {
        float* ob = out + S0 * 8 + (size_t)t * 4;
        ob[0] = bx1; ob[1] = by1; ob[2] = bx2; ob[3] = by2;
    }
    // target_corners
    {
        float* oc = out + S0 * 12 + (size_t)t * 8;
        #pragma unroll
        for (int i = 0; i < 8; ++i) oc[i] = gt_cn[row * 8 + i];
    }
    // scores: sparse scatter into pre-zeroed regions
    if (fgb) {
        out[S0 * 20 + (size_t)t * NPRO + (int)pro] = iou_pd;
        out[S0 * 20 + S0 * NPRO + (size_t)t * NALP + (int)alp] = iou_pd;
        const size_t ads_base = S0 * 20 + S0 * NPRO + S0 * NALP;
        #pragma unroll
        for (int i = 0; i < 6; ++i) {
            out[ads_base + (size_t)i * S0 * NADS + (size_t)t * NADS + (int)adsv[i]] = iou_pd;
        }
    }
    // fg_mask > 0 (bool as float)
    out[S0 * 20 + S0 * NPRO + S0 * NALP + (size_t)6 * S0 * NADS + t] = fgb ? 1.0f : 0.0f;
}

extern "C" void kernel_launch(void* const* d_in, const int* in_sizes, int n_in,
                              void* d_out, int out_size, void* d_ws, size_t ws_size,
                              hipStream_t stream) {
    const float* anc    = (const float*)d_in[0];
    // d_in[1] = n_level_bboxes (static: 25600, 6400, 1600) — hardcoded
    const float* gt_pro = (const float*)d_in[2];
    const float* gt_alp = (const float*)d_in[3];
    const float* gt_ads = (const float*)d_in[4];
    const float* gt_bb  = (const float*)d_in[5];
    const float* gt_cn  = (const float*)d_in[6];
    const float* mgt    = (const float*)d_in[7];
    const float* pd     = (const float*)d_in[8];

    unsigned long long* gbits = (unsigned long long*)d_ws;
    float* out = (float*)d_out;

    hipMemsetAsync(d_ws, 0, (size_t)NB * NA * sizeof(unsigned long long), stream);
    hipMemsetAsync(d_out, 0, (size_t)out_size * sizeof(float), stream);

    hipLaunchKernelGGL(k_cand, dim3(NB * NG), dim3(256), 0, stream,
                       anc, gt_bb, mgt, gbits);
    hipLaunchKernelGGL(k_assign, dim3((NB * NA) / 256), dim3(256), 0, stream,
                       anc, gt_pro, gt_alp, gt_ads, gt_bb, gt_cn, pd, gbits, out);
}